// Round 1
// baseline (419.874 us; speedup 1.0000x reference)
//
#include <hip/hip_runtime.h>
#include <hip/hip_bf16.h>

#define B 128
#define NPTS 2000
#define DD 256
#define HH 128
#define NHEAD 4
#define SPLITS 8
#define NEGV -1e8f
#define SCALE 0.0625f

typedef float f32x4 __attribute__((ext_vector_type(4)));
typedef __bf16 bf16x8 __attribute__((ext_vector_type(8)));

__device__ __forceinline__ float ftanh(float x) {
    float e = __expf(2.0f * x);
    return 1.0f - 2.0f / (e + 1.0f);
}
__device__ __forceinline__ float felu(float x) {
    return x > 0.0f ? x : __expf(x) - 1.0f;
}

// ---------------- preamble: ex-embedding MLP + query assembly ----------------
__global__ void k_embed(const float* __restrict__ raw,
                        const float* __restrict__ E1, const float* __restrict__ b1,
                        const float* __restrict__ E2, const float* __restrict__ b2,
                        const float* __restrict__ E3, const float* __restrict__ b3,
                        const float* __restrict__ v1, float* __restrict__ queryws) {
    int b = blockIdx.x, t = threadIdx.x;
    __shared__ float rs[6], h1[84], h2[64];
    if (t < 6) rs[t] = raw[b * 6 + t];
    __syncthreads();
    if (t < 84) {
        float a = b1[t];
        #pragma unroll
        for (int i = 0; i < 6; ++i) a += rs[i] * E1[i * 84 + t];
        h1[t] = felu(a);
    }
    __syncthreads();
    if (t < 64) {
        float a = b2[t];
        for (int i = 0; i < 84; ++i) a += h1[i] * E2[i * 64 + t];
        h2[t] = felu(a);
    }
    __syncthreads();
    float a = b3[t];
    for (int i = 0; i < 64; ++i) a += h2[i] * E3[i * 128 + t];
    queryws[b * 256 + t] = v1[t];
    queryws[b * 256 + 128 + t] = a;
}

// ---------------- qtil[b,m,d] = scale * sum_e Wk[m,d,e] * (sum_d' q[d'] Wq[m,d',e]) --
__global__ __launch_bounds__(256) void k_qtil(const float* __restrict__ queryws,
        const float* __restrict__ Wq, const float* __restrict__ Wk,
        float* __restrict__ qtilws) {
    int b = blockIdx.x, t = threadIdx.x;
    __shared__ float q[256];
    __shared__ float qh[NHEAD][256];
    q[t] = queryws[b * 256 + t];
    __syncthreads();
    #pragma unroll
    for (int m = 0; m < NHEAD; ++m) {
        float acc = 0.f;
        for (int d = 0; d < 256; ++d) acc += q[d] * Wq[(m * 256 + d) * 256 + t];
        qh[m][t] = acc;
    }
    __syncthreads();
    #pragma unroll
    for (int m = 0; m < NHEAD; ++m) {
        float acc = 0.f;
        for (int e = 0; e < 256; ++e) acc += Wk[(m * 256 + t) * 256 + e] * qh[m][e];
        qtilws[(b * NHEAD + m) * 256 + t] = acc * SCALE;
    }
}

// ---------------- pack Wref2 into bf16 MFMA B-fragment order ----------------
// frag = kt*16+nt ; element j of lane l is B[k = kt*32 + (l>>4)*8 + j][n = nt*16 + (l&15)]
__global__ void k_pack(const float* __restrict__ wref2, unsigned short* __restrict__ wpack) {
    int p0 = (blockIdx.x * 256 + threadIdx.x) * 4;
    #pragma unroll
    for (int qq = 0; qq < 4; ++qq) {
        int p = p0 + qq;
        int j = p & 7, l = (p >> 3) & 63, fr = p >> 9;
        int kt = fr >> 4, nt = fr & 15;
        int k = kt * 32 + (l >> 4) * 8 + j;
        int n = nt * 16 + (l & 15);
        __bf16 h = (__bf16)wref2[k * 256 + n];
        wpack[p] = __builtin_bit_cast(unsigned short, h);
    }
}

// ---------------- glimpse pass: scores + online softmax + weighted-feature partials --
__global__ __launch_bounds__(256) void k_glimpse(const float* __restrict__ feat,
        const int* __restrict__ mask, const float* __restrict__ qtil,
        float* __restrict__ pmax, float* __restrict__ psum, float* __restrict__ pfbar) {
    int bid = blockIdx.x;
    int b = bid / SPLITS, sp = bid % SPLITS;
    int w = threadIdx.x >> 6, l = threadIdx.x & 63;
    float4 qt[NHEAD];
    #pragma unroll
    for (int m = 0; m < NHEAD; ++m)
        qt[m] = *(const float4*)(qtil + ((b * NHEAD + m) << 8) + 4 * l);
    float rmax[NHEAD], rsum[NHEAD];
    float fx[NHEAD], fy[NHEAD], fz[NHEAD], fw[NHEAD];
    #pragma unroll
    for (int m = 0; m < NHEAD; ++m) {
        rmax[m] = -__builtin_huge_valf(); rsum[m] = 0.f;
        fx[m] = fy[m] = fz[m] = fw[m] = 0.f;
    }
    const int rows = NPTS / SPLITS;  // 250
    for (int r = w; r < rows; r += 4) {
        int n = sp * rows + r;
        const float4 f4 = *(const float4*)(feat + ((size_t)(b * NPTS + n) << 8) + 4 * l);
        int mk = mask[b * NPTS + n];
        #pragma unroll
        for (int m = 0; m < NHEAD; ++m) {
            float d = f4.x * qt[m].x + f4.y * qt[m].y + f4.z * qt[m].z + f4.w * qt[m].w;
            #pragma unroll
            for (int off = 1; off < 64; off <<= 1) d += __shfl_xor(d, off, 64);
            float s = mk ? d : NEGV;
            float nm = fmaxf(rmax[m], s);
            float corr = __expf(rmax[m] - nm);
            float wt = __expf(s - nm);
            rsum[m] = rsum[m] * corr + wt;
            fx[m] = fx[m] * corr + wt * f4.x;
            fy[m] = fy[m] * corr + wt * f4.y;
            fz[m] = fz[m] * corr + wt * f4.z;
            fw[m] = fw[m] * corr + wt * f4.w;
            rmax[m] = nm;
        }
    }
    __shared__ float smax[4][NHEAD], ssum[4][NHEAD];
    __shared__ float sfb[4][NHEAD][256];
    if (l == 0) {
        #pragma unroll
        for (int m = 0; m < NHEAD; ++m) { smax[w][m] = rmax[m]; ssum[w][m] = rsum[m]; }
    }
    #pragma unroll
    for (int m = 0; m < NHEAD; ++m) {
        sfb[w][m][4 * l + 0] = fx[m];
        sfb[w][m][4 * l + 1] = fy[m];
        sfb[w][m][4 * l + 2] = fz[m];
        sfb[w][m][4 * l + 3] = fw[m];
    }
    __syncthreads();
    int d = threadIdx.x;
    int pb = (b * SPLITS + sp) * NHEAD;
    #pragma unroll
    for (int m = 0; m < NHEAD; ++m) {
        float gmx = fmaxf(fmaxf(smax[0][m], smax[1][m]), fmaxf(smax[2][m], smax[3][m]));
        float acc = 0.f;
        #pragma unroll
        for (int ww = 0; ww < 4; ++ww) acc += sfb[ww][m][d] * __expf(smax[ww][m] - gmx);
        pfbar[(size_t)(pb + m) * 256 + d] = acc;
        if (threadIdx.x == 0) {
            float gs = 0.f;
            #pragma unroll
            for (int ww = 0; ww < 4; ++ww) gs += ssum[ww][m] * __expf(smax[ww][m] - gmx);
            pmax[pb + m] = gmx; psum[pb + m] = gs;
        }
    }
}

// ---------------- combine partials; g = fbar@Wv ; query = sum_m g@Wo ; q2 = query@Wq2 --
__global__ __launch_bounds__(256) void k_combine(const float* __restrict__ pmax,
        const float* __restrict__ psum, const float* __restrict__ pfbar,
        const float* __restrict__ Wv, const float* __restrict__ Wo,
        const float* __restrict__ Wq2, float* __restrict__ q2ws, float* __restrict__ outq) {
    int b = blockIdx.x, t = threadIdx.x;
    __shared__ float lpm[SPLITS][NHEAD], lps[SPLITS][NHEAD], gm[NHEAD], tm[NHEAD];
    __shared__ float fbar[NHEAD][256];
    __shared__ float g[NHEAD][256];
    __shared__ float qn[256];
    if (t < SPLITS * NHEAD) {
        int s = t >> 2, m = t & 3;
        lpm[s][m] = pmax[(b * SPLITS + s) * NHEAD + m];
        lps[s][m] = psum[(b * SPLITS + s) * NHEAD + m];
    }
    __syncthreads();
    if (t < NHEAD) {
        float gmx = -__builtin_huge_valf();
        for (int s = 0; s < SPLITS; ++s) gmx = fmaxf(gmx, lpm[s][t]);
        float ts = 0.f;
        for (int s = 0; s < SPLITS; ++s) ts += lps[s][t] * __expf(lpm[s][t] - gmx);
        gm[t] = gmx; tm[t] = ts;
    }
    __syncthreads();
    #pragma unroll
    for (int m = 0; m < NHEAD; ++m) {
        float fb = 0.f;
        for (int s = 0; s < SPLITS; ++s)
            fb += pfbar[(size_t)((b * SPLITS + s) * NHEAD + m) * 256 + t] * __expf(lpm[s][m] - gm[m]);
        fbar[m][t] = fb / tm[m];
    }
    __syncthreads();
    #pragma unroll
    for (int m = 0; m < NHEAD; ++m) {
        float acc = 0.f;
        for (int d = 0; d < 256; ++d) acc += fbar[m][d] * Wv[(m * 256 + d) * 256 + t];
        g[m][t] = acc;
    }
    __syncthreads();
    {
        float acc = 0.f;
        #pragma unroll
        for (int m = 0; m < NHEAD; ++m)
            for (int e = 0; e < 256; ++e) acc += g[m][e] * Wo[(m * 256 + e) * 256 + t];
        qn[t] = acc;
        outq[b * 256 + t] = acc;
    }
    __syncthreads();
    {
        float acc = 0.f;
        for (int d = 0; d < 256; ++d) acc += qn[d] * Wq2[d * 256 + t];
        q2ws[b * 256 + t] = acc;
    }
}

// ---------------- pointer head: u = 10*tanh( Vec2 . tanh(q2 + f@Wref2) ), fused MFMA --
__global__ __launch_bounds__(256, 2) void k_pointer(const float* __restrict__ feat,
        const int* __restrict__ mask, const unsigned short* __restrict__ wpack,
        const float* __restrict__ q2, const float* __restrict__ vec2,
        float* __restrict__ uout) {
    const int w = threadIdx.x >> 6, l = threadIdx.x & 63;
    const int lr = l & 15, lg = l >> 4;
    // hold this wave's 32 B-fragments (cols w*64 .. w*64+63, full K=256) in VGPRs
    bf16x8 bf[8][4];
    #pragma unroll
    for (int kt = 0; kt < 8; ++kt)
        #pragma unroll
        for (int i = 0; i < 4; ++i) {
            int frag = kt * 16 + (w * 4 + i);
            bf[kt][i] = *(const bf16x8*)(wpack + ((frag << 6) + l) * 8);
        }
    float v2[4];
    #pragma unroll
    for (int i = 0; i < 4; ++i) v2[i] = vec2[w * 64 + i * 16 + lr];
    __shared__ float lu[4][16];
    const int NT = (B * NPTS) / 16;  // 16000 tiles of 16 rows; 16 | 2000 so b uniform per tile
    for (int t = blockIdx.x; t < NT; t += gridDim.x) {
        int b = t / 125;
        int n0 = (t - b * 125) * 16;
        const float* ap = feat + ((size_t)(t * 16 + lr) << 8) + lg * 8;
        float q2v[4];
        #pragma unroll
        for (int i = 0; i < 4; ++i) q2v[i] = q2[b * 256 + w * 64 + i * 16 + lr];
        f32x4 acc[4];
        #pragma unroll
        for (int i = 0; i < 4; ++i)
            #pragma unroll
            for (int j = 0; j < 4; ++j) acc[i][j] = 0.f;
        #pragma unroll
        for (int kt = 0; kt < 8; ++kt) {
            float4 a0 = *(const float4*)(ap + kt * 32);
            float4 a1 = *(const float4*)(ap + kt * 32 + 4);
            bf16x8 af;
            af[0] = (__bf16)a0.x; af[1] = (__bf16)a0.y; af[2] = (__bf16)a0.z; af[3] = (__bf16)a0.w;
            af[4] = (__bf16)a1.x; af[5] = (__bf16)a1.y; af[6] = (__bf16)a1.z; af[7] = (__bf16)a1.w;
            #pragma unroll
            for (int i = 0; i < 4; ++i)
                acc[i] = __builtin_amdgcn_mfma_f32_16x16x32_bf16(af, bf[kt][i], acc[i], 0, 0, 0);
        }
        // epilogue: rows 4*lg+j, cols w*64+i*16+lr
        float s0 = 0.f, s1 = 0.f, s2 = 0.f, s3 = 0.f;
        #pragma unroll
        for (int i = 0; i < 4; ++i) {
            float qv = q2v[i], vv = v2[i];
            s0 += ftanh(acc[i][0] + qv) * vv;
            s1 += ftanh(acc[i][1] + qv) * vv;
            s2 += ftanh(acc[i][2] + qv) * vv;
            s3 += ftanh(acc[i][3] + qv) * vv;
        }
        #pragma unroll
        for (int off = 1; off < 16; off <<= 1) {
            s0 += __shfl_xor(s0, off, 64);
            s1 += __shfl_xor(s1, off, 64);
            s2 += __shfl_xor(s2, off, 64);
            s3 += __shfl_xor(s3, off, 64);
        }
        if (lr == 0) {
            lu[w][lg * 4 + 0] = s0; lu[w][lg * 4 + 1] = s1;
            lu[w][lg * 4 + 2] = s2; lu[w][lg * 4 + 3] = s3;
        }
        __syncthreads();
        if (threadIdx.x < 16) {
            int r = threadIdx.x;
            float tot = lu[0][r] + lu[1][r] + lu[2][r] + lu[3][r];
            float uu = 10.f * ftanh(tot);
            int n = n0 + r;
            if (mask[b * NPTS + n] == 0) uu = NEGV;
            uout[b * NPTS + n] = uu;
        }
        __syncthreads();
    }
}

// ---------------- log-softmax over N per batch ----------------
__global__ __launch_bounds__(256) void k_lse(const float* __restrict__ u, float* __restrict__ outp) {
    int b = blockIdx.x, t = threadIdx.x;
    float uv[8];
    int cnt = 0;
    float mx = -__builtin_huge_valf();
    for (int i = t; i < NPTS; i += 256) { uv[cnt] = u[b * NPTS + i]; mx = fmaxf(mx, uv[cnt]); ++cnt; }
    __shared__ float red[4];
    #pragma unroll
    for (int off = 1; off < 64; off <<= 1) mx = fmaxf(mx, __shfl_xor(mx, off, 64));
    int w = t >> 6, l = t & 63;
    if (l == 0) red[w] = mx;
    __syncthreads();
    mx = fmaxf(fmaxf(red[0], red[1]), fmaxf(red[2], red[3]));
    __syncthreads();
    float sm = 0.f;
    for (int c = 0; c < cnt; ++c) sm += __expf(uv[c] - mx);
    #pragma unroll
    for (int off = 1; off < 64; off <<= 1) sm += __shfl_xor(sm, off, 64);
    if (l == 0) red[w] = sm;
    __syncthreads();
    sm = red[0] + red[1] + red[2] + red[3];
    float lse = mx + __logf(sm);
    cnt = 0;
    for (int i = t; i < NPTS; i += 256) { outp[b * NPTS + i] = uv[cnt] - lse; ++cnt; }
}

extern "C" void kernel_launch(void* const* d_in, const int* in_sizes, int n_in,
                              void* d_out, int out_size, void* d_ws, size_t ws_size,
                              hipStream_t stream) {
    const float* feat = (const float*)d_in[0];
    const float* raw  = (const float*)d_in[1];
    const int*   mask = (const int*)d_in[2];
    const float* E1 = (const float*)d_in[3];
    const float* b1 = (const float*)d_in[4];
    const float* E2 = (const float*)d_in[5];
    const float* b2 = (const float*)d_in[6];
    const float* E3 = (const float*)d_in[7];
    const float* b3 = (const float*)d_in[8];
    const float* Wq = (const float*)d_in[9];
    const float* Wk = (const float*)d_in[10];
    const float* Wv = (const float*)d_in[11];
    const float* Wo = (const float*)d_in[12];
    const float* Wq2 = (const float*)d_in[13];
    const float* Wref2 = (const float*)d_in[14];
    const float* Vec2 = (const float*)d_in[15];
    const float* v1 = (const float*)d_in[16];
    float* out = (float*)d_out;

    char* ws = (char*)d_ws;
    float* queryws = (float*)(ws + 0);             // 131072 B
    float* qtilws  = (float*)(ws + 131072);        // 524288 B
    float* pmax    = (float*)(ws + 655360);        // 16384 B
    float* psum    = (float*)(ws + 671744);        // 16384 B
    float* pfbar   = (float*)(ws + 688128);        // 4194304 B
    float* q2ws    = (float*)(ws + 4882432);       // 131072 B
    unsigned short* wpack = (unsigned short*)(ws + 5013504);  // 131072 B
    float* uws     = (float*)(ws + 5144576);       // 1024000 B
    float* outq = out + B * NPTS;

    hipLaunchKernelGGL(k_embed, dim3(B), dim3(128), 0, stream,
                       raw, E1, b1, E2, b2, E3, b3, v1, queryws);
    hipLaunchKernelGGL(k_pack, dim3(64), dim3(256), 0, stream, Wref2, wpack);
    hipLaunchKernelGGL(k_qtil, dim3(B), dim3(256), 0, stream, queryws, Wq, Wk, qtilws);
    hipLaunchKernelGGL(k_glimpse, dim3(B * SPLITS), dim3(256), 0, stream,
                       feat, mask, qtilws, pmax, psum, pfbar);
    hipLaunchKernelGGL(k_combine, dim3(B), dim3(256), 0, stream,
                       pmax, psum, pfbar, Wv, Wo, Wq2, q2ws, outq);
    hipLaunchKernelGGL(k_pointer, dim3(512), dim3(256), 0, stream,
                       feat, mask, wpack, q2ws, Vec2, uws);
    hipLaunchKernelGGL(k_lse, dim3(B), dim3(256), 0, stream, uws, out);
}

// Round 2
// 306.260 us; speedup vs baseline: 1.3710x; 1.3710x over previous
//
#include <hip/hip_runtime.h>
#include <hip/hip_bf16.h>

#define B 128
#define NPTS 2000
#define NHEAD 4
#define SPLITS 8
#define NEGV -1e8f
#define SCALE 0.0625f

typedef float f32x4 __attribute__((ext_vector_type(4)));
typedef __bf16 bf16x8 __attribute__((ext_vector_type(8)));

__device__ __forceinline__ float ftanh(float x) {
    float e = __expf(2.0f * x);
    return 1.0f - 2.0f / (e + 1.0f);
}
__device__ __forceinline__ float felu(float x) {
    return x > 0.0f ? x : __expf(x) - 1.0f;
}

// ---------------- preamble: ex-embedding MLP + query assembly ----------------
__global__ void k_embed(const float* __restrict__ raw,
                        const float* __restrict__ E1, const float* __restrict__ b1,
                        const float* __restrict__ E2, const float* __restrict__ b2,
                        const float* __restrict__ E3, const float* __restrict__ b3,
                        const float* __restrict__ v1, float* __restrict__ queryws) {
    int b = blockIdx.x, t = threadIdx.x;
    __shared__ float rs[6], h1[84], h2[64];
    if (t < 6) rs[t] = raw[b * 6 + t];
    __syncthreads();
    if (t < 84) {
        float a = b1[t];
        #pragma unroll
        for (int i = 0; i < 6; ++i) a += rs[i] * E1[i * 84 + t];
        h1[t] = felu(a);
    }
    __syncthreads();
    if (t < 64) {
        float a = b2[t];
        for (int i = 0; i < 84; ++i) a += h1[i] * E2[i * 64 + t];
        h2[t] = felu(a);
    }
    __syncthreads();
    float a = b3[t];
    for (int i = 0; i < 64; ++i) a += h2[i] * E3[i * 128 + t];
    queryws[b * 256 + t] = v1[t];
    queryws[b * 256 + 128 + t] = a;
}

// ---------------- qtil[b,m,d] = scale * Wk[m]@(Wq[m]^T q) ----------------
__global__ __launch_bounds__(256) void k_qtil(const float* __restrict__ queryws,
        const float* __restrict__ Wq, const float* __restrict__ Wk,
        float* __restrict__ qtilws) {
    int b = blockIdx.x, t = threadIdx.x;
    __shared__ float q[256];
    __shared__ float qh[NHEAD][256];
    q[t] = queryws[b * 256 + t];
    __syncthreads();
    #pragma unroll
    for (int m = 0; m < NHEAD; ++m) {
        float acc = 0.f;
        for (int d = 0; d < 256; ++d) acc += q[d] * Wq[(m * 256 + d) * 256 + t];
        qh[m][t] = acc;
    }
    __syncthreads();
    #pragma unroll
    for (int m = 0; m < NHEAD; ++m) {
        float acc = 0.f;
        for (int e = 0; e < 256; ++e) acc += Wk[(m * 256 + t) * 256 + e] * qh[m][e];
        qtilws[(b * NHEAD + m) * 256 + t] = acc * SCALE;
    }
}

// ---------------- pack Wref2 into bf16 MFMA B-fragment order ----------------
__global__ void k_pack(const float* __restrict__ wref2, unsigned short* __restrict__ wpack) {
    int p0 = (blockIdx.x * 256 + threadIdx.x) * 4;
    #pragma unroll
    for (int qq = 0; qq < 4; ++qq) {
        int p = p0 + qq;
        int j = p & 7, l = (p >> 3) & 63, fr = p >> 9;
        int kt = fr >> 4, nt = fr & 15;
        int k = kt * 32 + (l >> 4) * 8 + j;
        int n = nt * 16 + (l & 15);
        __bf16 h = (__bf16)wref2[k * 256 + n];
        wpack[p] = __builtin_bit_cast(unsigned short, h);
    }
}

// ---------------- glimpse: 4 rows/wave, 16 lanes/row, defer-max online softmax ----
__global__ __launch_bounds__(256, 2) void k_glimpse(const float* __restrict__ feat,
        const int* __restrict__ mask, const float* __restrict__ qtil,
        float* __restrict__ pmax, float* __restrict__ psum, float* __restrict__ pfbar) {
    int bid = blockIdx.x;
    int b = bid / SPLITS, sp = bid % SPLITS;
    int w = threadIdx.x >> 6, l = threadIdx.x & 63;
    int g = l >> 4, c = l & 15;          // row-subgroup, d-chunk
    const int base = sp * (NPTS / SPLITS);   // 250 rows per split

    f32x4 qt[NHEAD][4];
    #pragma unroll
    for (int m = 0; m < NHEAD; ++m)
        #pragma unroll
        for (int q4 = 0; q4 < 4; ++q4)
            qt[m][q4] = *(const f32x4*)(qtil + ((b * NHEAD + m) << 8) + c * 16 + q4 * 4);

    float rmax[NHEAD], rsum[NHEAD];
    f32x4 fb[NHEAD][4];
    #pragma unroll
    for (int m = 0; m < NHEAD; ++m) {
        rmax[m] = -__builtin_huge_valf(); rsum[m] = 0.f;
        #pragma unroll
        for (int q4 = 0; q4 < 4; ++q4) fb[m][q4] = 0.f;
    }

    const int sub = w * 4 + g;           // 0..15
    for (int it = 0; it < 16; ++it) {
        int rr = it * 16 + sub;          // 0..255
        bool valid = rr < 250;
        int n = base + (valid ? rr : 0);
        const float* fp = feat + ((size_t)(b * NPTS + n) << 8) + c * 16;
        f32x4 f0 = *(const f32x4*)(fp + 0);
        f32x4 f1 = *(const f32x4*)(fp + 4);
        f32x4 f2 = *(const f32x4*)(fp + 8);
        f32x4 f3 = *(const f32x4*)(fp + 12);
        int mk = valid ? mask[b * NPTS + n] : 0;
        #pragma unroll
        for (int m = 0; m < NHEAD; ++m) {
            f32x4 tv = f0 * qt[m][0] + f1 * qt[m][1] + f2 * qt[m][2] + f3 * qt[m][3];
            float s = tv.x + tv.y + tv.z + tv.w;
            s += __shfl_xor(s, 1, 64);
            s += __shfl_xor(s, 2, 64);
            s += __shfl_xor(s, 4, 64);
            s += __shfl_xor(s, 8, 64);
            s = mk ? s : NEGV;
            if (s > rmax[m] + 8.f) {     // defer-max: rare rescale
                float cr = __expf(rmax[m] - s);
                rsum[m] *= cr;
                #pragma unroll
                for (int q4 = 0; q4 < 4; ++q4) fb[m][q4] *= cr;
                rmax[m] = s;
            }
            float wt = __expf(s - rmax[m]);
            rsum[m] += wt;
            fb[m][0] += wt * f0; fb[m][1] += wt * f1;
            fb[m][2] += wt * f2; fb[m][3] += wt * f3;
        }
    }

    // block combine: 16 (wave,group) partial states
    __shared__ float sfb[16 * NHEAD * 256];   // 64 KB
    __shared__ float smax[16][NHEAD], ssum[16][NHEAD];
    #pragma unroll
    for (int m = 0; m < NHEAD; ++m) {
        #pragma unroll
        for (int q4 = 0; q4 < 4; ++q4)
            *(f32x4*)&sfb[(sub * NHEAD + m) * 256 + c * 16 + q4 * 4] = fb[m][q4];
        if (c == 0) { smax[sub][m] = rmax[m]; ssum[sub][m] = rsum[m]; }
    }
    __syncthreads();
    int t = threadIdx.x;
    int pb = (b * SPLITS + sp) * NHEAD;
    #pragma unroll
    for (int m = 0; m < NHEAD; ++m) {
        float gmx = -__builtin_huge_valf();
        #pragma unroll
        for (int wg = 0; wg < 16; ++wg) gmx = fmaxf(gmx, smax[wg][m]);
        float acc = 0.f;
        #pragma unroll
        for (int wg = 0; wg < 16; ++wg)
            acc += sfb[(wg * NHEAD + m) * 256 + t] * __expf(smax[wg][m] - gmx);
        pfbar[(size_t)(pb + m) * 256 + t] = acc;
        if (t == 0) {
            float gs = 0.f;
            #pragma unroll
            for (int wg = 0; wg < 16; ++wg) gs += ssum[wg][m] * __expf(smax[wg][m] - gmx);
            pmax[pb + m] = gmx; psum[pb + m] = gs;
        }
    }
}

// ---------------- combine partials; g=fbar@Wv; query=sum g@Wo; q2=query@Wq2 ----
__global__ __launch_bounds__(256) void k_combine(const float* __restrict__ pmax,
        const float* __restrict__ psum, const float* __restrict__ pfbar,
        const float* __restrict__ Wv, const float* __restrict__ Wo,
        const float* __restrict__ Wq2, float* __restrict__ q2ws, float* __restrict__ outq) {
    int b = blockIdx.x, t = threadIdx.x;
    __shared__ float lpm[SPLITS][NHEAD], lps[SPLITS][NHEAD], gm[NHEAD], tm[NHEAD];
    __shared__ float fbar[NHEAD][256];
    __shared__ float g[NHEAD][256];
    __shared__ float qn[256];
    if (t < SPLITS * NHEAD) {
        int s = t >> 2, m = t & 3;
        lpm[s][m] = pmax[(b * SPLITS + s) * NHEAD + m];
        lps[s][m] = psum[(b * SPLITS + s) * NHEAD + m];
    }
    __syncthreads();
    if (t < NHEAD) {
        float gmx = -__builtin_huge_valf();
        for (int s = 0; s < SPLITS; ++s) gmx = fmaxf(gmx, lpm[s][t]);
        float ts = 0.f;
        for (int s = 0; s < SPLITS; ++s) ts += lps[s][t] * __expf(lpm[s][t] - gmx);
        gm[t] = gmx; tm[t] = ts;
    }
    __syncthreads();
    #pragma unroll
    for (int m = 0; m < NHEAD; ++m) {
        float fbv = 0.f;
        for (int s = 0; s < SPLITS; ++s)
            fbv += pfbar[(size_t)((b * SPLITS + s) * NHEAD + m) * 256 + t] * __expf(lpm[s][m] - gm[m]);
        fbar[m][t] = fbv / tm[m];
    }
    __syncthreads();
    #pragma unroll
    for (int m = 0; m < NHEAD; ++m) {
        float acc = 0.f;
        for (int d = 0; d < 256; ++d) acc += fbar[m][d] * Wv[(m * 256 + d) * 256 + t];
        g[m][t] = acc;
    }
    __syncthreads();
    {
        float acc = 0.f;
        #pragma unroll
        for (int m = 0; m < NHEAD; ++m)
            for (int e = 0; e < 256; ++e) acc += g[m][e] * Wo[(m * 256 + e) * 256 + t];
        qn[t] = acc;
        outq[b * 256 + t] = acc;
    }
    __syncthreads();
    {
        float acc = 0.f;
        for (int d = 0; d < 256; ++d) acc += qn[d] * Wq2[d * 256 + t];
        q2ws[b * 256 + t] = acc;
    }
}

// ---------------- pointer head: cooperative LDS-staged MFMA, per-wave e-slice partials --
#define PGRID 512
__global__ __launch_bounds__(256, 2) void k_pointer(const float* __restrict__ feat,
        const unsigned short* __restrict__ wpack, const float* __restrict__ q2,
        const float* __restrict__ vec2, float* __restrict__ upart) {
    const int tid = threadIdx.x;
    const int w = tid >> 6, l = tid & 63;
    const int lr = l & 15, lg = l >> 4;
    // B-fragments: wave w owns e-cols w*64..w*64+63
    bf16x8 bf[8][4];
    #pragma unroll
    for (int kt = 0; kt < 8; ++kt)
        #pragma unroll
        for (int i = 0; i < 4; ++i) {
            int frag = kt * 16 + (w * 4 + i);
            bf[kt][i] = *(const bf16x8*)(wpack + ((frag << 6) + l) * 8);
        }
    float v2[4];
    #pragma unroll
    for (int i = 0; i < 4; ++i) v2[i] = vec2[w * 64 + i * 16 + lr];

    __shared__ char AB[16384];           // 2 x [16 rows][256 bf16], XOR-swizzled
    // staging geometry (all 256 threads): row = tid>>4, chunk c = tid&15 (16 floats)
    const int srow = tid >> 4, sc = tid & 15;
    const int swz = (srow & 7) << 4;
    const int NT = (B * NPTS) / 16;      // 16000

    int t0 = blockIdx.x;
    // prologue: stage tile t0 into buffer 0
    {
        const float* gp = feat + ((size_t)(t0 * 16 + srow) << 8) + sc * 16;
        f32x4 a = *(const f32x4*)(gp + 0), b4 = *(const f32x4*)(gp + 4);
        f32x4 cc = *(const f32x4*)(gp + 8), d = *(const f32x4*)(gp + 12);
        bf16x8 h0, h1;
        h0[0]=(__bf16)a.x; h0[1]=(__bf16)a.y; h0[2]=(__bf16)a.z; h0[3]=(__bf16)a.w;
        h0[4]=(__bf16)b4.x; h0[5]=(__bf16)b4.y; h0[6]=(__bf16)b4.z; h0[7]=(__bf16)b4.w;
        h1[0]=(__bf16)cc.x; h1[1]=(__bf16)cc.y; h1[2]=(__bf16)cc.z; h1[3]=(__bf16)cc.w;
        h1[4]=(__bf16)d.x; h1[5]=(__bf16)d.y; h1[6]=(__bf16)d.z; h1[7]=(__bf16)d.w;
        *(bf16x8*)(AB + srow * 512 + ((sc * 32) ^ swz)) = h0;
        *(bf16x8*)(AB + srow * 512 + ((sc * 32 + 16) ^ swz)) = h1;
    }
    int cur = 0;
    for (int t = t0; t < NT; t += PGRID) {
        int tn = t + PGRID;
        bool has = tn < NT;
        int tl = has ? tn : t;
        // prefetch next tile into regs (in flight during compute)
        const float* gp = feat + ((size_t)(tl * 16 + srow) << 8) + sc * 16;
        f32x4 pa = *(const f32x4*)(gp + 0), pb = *(const f32x4*)(gp + 4);
        f32x4 pc = *(const f32x4*)(gp + 8), pd = *(const f32x4*)(gp + 12);

        __syncthreads();                 // buf[cur] ready; prev reads of buf[cur^1] done
        // ---- compute tile t from buf[cur] ----
        int b = t / 125;
        int n0 = (t - b * 125) * 16;
        float q2v[4];
        #pragma unroll
        for (int i = 0; i < 4; ++i) q2v[i] = q2[b * 256 + w * 64 + i * 16 + lr];
        f32x4 acc[4];
        #pragma unroll
        for (int i = 0; i < 4; ++i) acc[i] = 0.f;
        const char* rb = AB + cur * 8192 + lr * 512;
        const int rswz = (lr & 7) << 4;
        #pragma unroll
        for (int kt = 0; kt < 8; ++kt) {
            bf16x8 af = *(const bf16x8*)(rb + ((kt * 64 + lg * 16) ^ rswz));
            #pragma unroll
            for (int i = 0; i < 4; ++i)
                acc[i] = __builtin_amdgcn_mfma_f32_16x16x32_bf16(af, bf[kt][i], acc[i], 0, 0, 0);
        }
        float s0 = 0.f, s1 = 0.f, s2 = 0.f, s3 = 0.f;
        #pragma unroll
        for (int i = 0; i < 4; ++i) {
            float qv = q2v[i], vv = v2[i];
            s0 += ftanh(acc[i][0] + qv) * vv;
            s1 += ftanh(acc[i][1] + qv) * vv;
            s2 += ftanh(acc[i][2] + qv) * vv;
            s3 += ftanh(acc[i][3] + qv) * vv;
        }
        #pragma unroll
        for (int off = 1; off < 16; off <<= 1) {
            s0 += __shfl_xor(s0, off, 64);
            s1 += __shfl_xor(s1, off, 64);
            s2 += __shfl_xor(s2, off, 64);
            s3 += __shfl_xor(s3, off, 64);
        }
        if (lr == 0) {
            float* up = upart + (size_t)w * (B * NPTS) + b * NPTS + n0 + lg * 4;
            up[0] = s0; up[1] = s1; up[2] = s2; up[3] = s3;
        }
        // ---- stage prefetched tile into buf[cur^1] ----
        if (has) {
            bf16x8 h0, h1;
            h0[0]=(__bf16)pa.x; h0[1]=(__bf16)pa.y; h0[2]=(__bf16)pa.z; h0[3]=(__bf16)pa.w;
            h0[4]=(__bf16)pb.x; h0[5]=(__bf16)pb.y; h0[6]=(__bf16)pb.z; h0[7]=(__bf16)pb.w;
            h1[0]=(__bf16)pc.x; h1[1]=(__bf16)pc.y; h1[2]=(__bf16)pc.z; h1[3]=(__bf16)pc.w;
            h1[4]=(__bf16)pd.x; h1[5]=(__bf16)pd.y; h1[6]=(__bf16)pd.z; h1[7]=(__bf16)pd.w;
            char* wb = AB + (cur ^ 1) * 8192 + srow * 512;
            *(bf16x8*)(wb + ((sc * 32) ^ swz)) = h0;
            *(bf16x8*)(wb + ((sc * 32 + 16) ^ swz)) = h1;
        }
        cur ^= 1;
    }
}

// ---------------- combine 4 e-slice partials + 10*tanh + mask + log-softmax ----
__global__ __launch_bounds__(256) void k_lse(const float* __restrict__ upart,
        const int* __restrict__ mask, float* __restrict__ outp) {
    int b = blockIdx.x, t = threadIdx.x;
    const float* u0 = upart + b * NPTS;
    const float* u1 = upart + (size_t)1 * B * NPTS + b * NPTS;
    const float* u2 = upart + (size_t)2 * B * NPTS + b * NPTS;
    const float* u3 = upart + (size_t)3 * B * NPTS + b * NPTS;
    float uv[8];
    int cnt = 0;
    float mx = -__builtin_huge_valf();
    for (int i = t; i < NPTS; i += 256) {
        float tot = u0[i] + u1[i] + u2[i] + u3[i];
        float uu = 10.f * ftanh(tot);
        if (mask[b * NPTS + i] == 0) uu = NEGV;
        uv[cnt] = uu; mx = fmaxf(mx, uu); ++cnt;
    }
    __shared__ float red[4];
    #pragma unroll
    for (int off = 1; off < 64; off <<= 1) mx = fmaxf(mx, __shfl_xor(mx, off, 64));
    int w = t >> 6, l = t & 63;
    if (l == 0) red[w] = mx;
    __syncthreads();
    mx = fmaxf(fmaxf(red[0], red[1]), fmaxf(red[2], red[3]));
    __syncthreads();
    float sm = 0.f;
    for (int c = 0; c < cnt; ++c) sm += __expf(uv[c] - mx);
    #pragma unroll
    for (int off = 1; off < 64; off <<= 1) sm += __shfl_xor(sm, off, 64);
    if (l == 0) red[w] = sm;
    __syncthreads();
    sm = red[0] + red[1] + red[2] + red[3];
    float lse = mx + __logf(sm);
    cnt = 0;
    for (int i = t; i < NPTS; i += 256) { outp[b * NPTS + i] = uv[cnt] - lse; ++cnt; }
}

extern "C" void kernel_launch(void* const* d_in, const int* in_sizes, int n_in,
                              void* d_out, int out_size, void* d_ws, size_t ws_size,
                              hipStream_t stream) {
    const float* feat = (const float*)d_in[0];
    const float* raw  = (const float*)d_in[1];
    const int*   mask = (const int*)d_in[2];
    const float* E1 = (const float*)d_in[3];
    const float* b1 = (const float*)d_in[4];
    const float* E2 = (const float*)d_in[5];
    const float* b2 = (const float*)d_in[6];
    const float* E3 = (const float*)d_in[7];
    const float* b3 = (const float*)d_in[8];
    const float* Wq = (const float*)d_in[9];
    const float* Wk = (const float*)d_in[10];
    const float* Wv = (const float*)d_in[11];
    const float* Wo = (const float*)d_in[12];
    const float* Wq2 = (const float*)d_in[13];
    const float* Wref2 = (const float*)d_in[14];
    const float* Vec2 = (const float*)d_in[15];
    const float* v1 = (const float*)d_in[16];
    float* out = (float*)d_out;

    char* ws = (char*)d_ws;
    float* queryws = (float*)(ws + 0);             // 131072 B
    float* qtilws  = (float*)(ws + 131072);        // 524288 B
    float* pmax    = (float*)(ws + 655360);        // 16384 B
    float* psum    = (float*)(ws + 671744);        // 16384 B
    float* pfbar   = (float*)(ws + 688128);        // 4194304 B (overlaid by upart after k_combine)
    float* q2ws    = (float*)(ws + 4882432);       // 131072 B
    unsigned short* wpack = (unsigned short*)(ws + 5013504);  // 131072 B
    float* upart   = (float*)(ws + 688128);        // 4 x 128 x 2000 x 4 = 4096000 B (overlay on pfbar)
    float* outq = out + B * NPTS;

    hipLaunchKernelGGL(k_embed, dim3(B), dim3(128), 0, stream,
                       raw, E1, b1, E2, b2, E3, b3, v1, queryws);
    hipLaunchKernelGGL(k_pack, dim3(64), dim3(256), 0, stream, Wref2, wpack);
    hipLaunchKernelGGL(k_qtil, dim3(B), dim3(256), 0, stream, queryws, Wq, Wk, qtilws);
    hipLaunchKernelGGL(k_glimpse, dim3(B * SPLITS), dim3(256), 0, stream,
                       feat, mask, qtilws, pmax, psum, pfbar);
    hipLaunchKernelGGL(k_combine, dim3(B), dim3(256), 0, stream,
                       pmax, psum, pfbar, Wv, Wo, Wq2, q2ws, outq);
    hipLaunchKernelGGL(k_pointer, dim3(PGRID), dim3(256), 0, stream,
                       feat, wpack, q2ws, Vec2, upart);
    hipLaunchKernelGGL(k_lse, dim3(B), dim3(256), 0, stream, upart, mask, out);
}

// Round 3
// 288.991 us; speedup vs baseline: 1.4529x; 1.0598x over previous
//
#include <hip/hip_runtime.h>
#include <hip/hip_bf16.h>

#define B 128
#define NPTS 2000
#define NHEAD 4
#define SPLITS 8
#define NEGV -1e8f
#define SCALE 0.0625f
#define PGRID 512

typedef float f32x4 __attribute__((ext_vector_type(4)));
typedef __bf16 bf16x8 __attribute__((ext_vector_type(8)));

__device__ __forceinline__ float ftanh(float x) {
    float e = __expf(2.0f * x);
    return 1.0f - 2.0f / (e + 1.0f);
}
__device__ __forceinline__ float felu(float x) {
    return x > 0.0f ? x : __expf(x) - 1.0f;
}

// ---- fused preamble: (blocks < B) embed MLP + query + qtil ; (blocks >= B) pack Wref2 --
__global__ __launch_bounds__(256) void k_prep(const float* __restrict__ raw,
        const float* __restrict__ E1, const float* __restrict__ b1,
        const float* __restrict__ E2, const float* __restrict__ b2,
        const float* __restrict__ E3, const float* __restrict__ b3,
        const float* __restrict__ v1,
        const float* __restrict__ Wq, const float* __restrict__ Wk,
        const float* __restrict__ wref2,
        float* __restrict__ queryws, float* __restrict__ qtilws,
        unsigned short* __restrict__ wpack) {
    int t = threadIdx.x;
    if (blockIdx.x >= B) {
        int p0 = ((blockIdx.x - B) * 256 + t) * 4;
        #pragma unroll
        for (int qq = 0; qq < 4; ++qq) {
            int p = p0 + qq;
            int j = p & 7, l = (p >> 3) & 63, fr = p >> 9;
            int kt = fr >> 4, nt = fr & 15;
            int k = kt * 32 + (l >> 4) * 8 + j;
            int n = nt * 16 + (l & 15);
            __bf16 h = (__bf16)wref2[k * 256 + n];
            wpack[p] = __builtin_bit_cast(unsigned short, h);
        }
        return;
    }
    int b = blockIdx.x;
    __shared__ float rs[6], h1[84], h2[64];
    __shared__ float q[256];
    __shared__ float qh[NHEAD][256];
    if (t < 6) rs[t] = raw[b * 6 + t];
    __syncthreads();
    if (t < 84) {
        float a = b1[t];
        #pragma unroll
        for (int i = 0; i < 6; ++i) a += rs[i] * E1[i * 84 + t];
        h1[t] = felu(a);
    }
    __syncthreads();
    if (t < 64) {
        float a = b2[t];
        for (int i = 0; i < 84; ++i) a += h1[i] * E2[i * 64 + t];
        h2[t] = felu(a);
    }
    __syncthreads();
    if (t < 128) {
        float a = b3[t];
        for (int i = 0; i < 64; ++i) a += h2[i] * E3[i * 128 + t];
        q[t] = v1[t];
        q[128 + t] = a;
        queryws[b * 256 + t] = v1[t];
        queryws[b * 256 + 128 + t] = a;
    }
    __syncthreads();
    #pragma unroll
    for (int m = 0; m < NHEAD; ++m) {
        float acc = 0.f;
        for (int d = 0; d < 256; ++d) acc += q[d] * Wq[(m * 256 + d) * 256 + t];
        qh[m][t] = acc;
    }
    __syncthreads();
    #pragma unroll
    for (int m = 0; m < NHEAD; ++m) {
        float acc = 0.f;
        for (int e = 0; e < 256; ++e) acc += Wk[(m * 256 + t) * 256 + e] * qh[m][e];
        qtilws[(b * NHEAD + m) * 256 + t] = acc * SCALE;
    }
}

// ---- glimpse: 32-lane rows, branchless online softmax, reg ping-pong prefetch ----
__global__ __launch_bounds__(256, 4) void k_glimpse(const float* __restrict__ feat,
        const int* __restrict__ mask, const float* __restrict__ qtil,
        float* __restrict__ pmax, float* __restrict__ psum, float* __restrict__ pfbar) {
    int bid = blockIdx.x;
    int b = bid / SPLITS, sp = bid % SPLITS;
    int w = threadIdx.x >> 6;
    int h = (threadIdx.x >> 5) & 1;
    int c = threadIdx.x & 31;            // 8-float chunk
    const int sub = w * 2 + h;           // 0..7 row-streams
    const int base = sp * (NPTS / SPLITS);

    f32x4 qt[NHEAD][2];
    #pragma unroll
    for (int m = 0; m < NHEAD; ++m) {
        qt[m][0] = *(const f32x4*)(qtil + ((b * NHEAD + m) << 8) + c * 8);
        qt[m][1] = *(const f32x4*)(qtil + ((b * NHEAD + m) << 8) + c * 8 + 4);
    }
    float rmax[NHEAD], rsum[NHEAD];
    f32x4 fb[NHEAD][2];
    #pragma unroll
    for (int m = 0; m < NHEAD; ++m) {
        rmax[m] = -__builtin_huge_valf(); rsum[m] = 0.f;
        fb[m][0] = 0.f; fb[m][1] = 0.f;
    }

    // ping-pong prefetch over 32 iterations (rows rr = it*8 + sub)
    f32x4 a0, a1; int mka;
    {
        int rr = sub;
        int n = base + rr;
        const float* fp = feat + ((size_t)(b * NPTS + n) << 8) + c * 8;
        a0 = *(const f32x4*)fp; a1 = *(const f32x4*)(fp + 4);
        mka = mask[b * NPTS + n];
    }
    for (int it = 0; it < 32; ++it) {
        // issue next row's loads
        int rr2 = (it + 1) * 8 + sub;
        bool v2ok = rr2 < 250;
        int n2 = base + (v2ok ? rr2 : sub);
        const float* fp2 = feat + ((size_t)(b * NPTS + n2) << 8) + c * 8;
        f32x4 b0 = *(const f32x4*)fp2;
        f32x4 b1 = *(const f32x4*)(fp2 + 4);
        int mkb = v2ok ? mask[b * NPTS + n2] : 0;
        // process current row
        int rr = it * 8 + sub;
        int mk = (rr < 250) ? mka : 0;
        #pragma unroll
        for (int m = 0; m < NHEAD; ++m) {
            f32x4 tv = a0 * qt[m][0] + a1 * qt[m][1];
            float s = tv.x + tv.y + tv.z + tv.w;
            s += __shfl_xor(s, 1, 64);
            s += __shfl_xor(s, 2, 64);
            s += __shfl_xor(s, 4, 64);
            s += __shfl_xor(s, 8, 64);
            s += __shfl_xor(s, 16, 64);
            s = mk ? s : NEGV;
            float nm = fmaxf(rmax[m], s);
            float cr = __expf(rmax[m] - nm);
            float wt = __expf(s - nm);
            rsum[m] = rsum[m] * cr + wt;
            fb[m][0] = fb[m][0] * cr + wt * a0;
            fb[m][1] = fb[m][1] * cr + wt * a1;
            rmax[m] = nm;
        }
        a0 = b0; a1 = b1; mka = mkb;
    }

    // block combine: 8 row-stream partials, per-head LDS rounds
    __shared__ float sfb[8][256];
    __shared__ float smax[8][NHEAD], ssum[8][NHEAD];
    if (c == 0) {
        #pragma unroll
        for (int m = 0; m < NHEAD; ++m) { smax[sub][m] = rmax[m]; ssum[sub][m] = rsum[m]; }
    }
    int t = threadIdx.x;
    int pb = (b * SPLITS + sp) * NHEAD;
    #pragma unroll
    for (int m = 0; m < NHEAD; ++m) {
        __syncthreads();
        *(f32x4*)&sfb[sub][c * 8] = fb[m][0];
        *(f32x4*)&sfb[sub][c * 8 + 4] = fb[m][1];
        __syncthreads();
        float gmx = -__builtin_huge_valf();
        #pragma unroll
        for (int wg = 0; wg < 8; ++wg) gmx = fmaxf(gmx, smax[wg][m]);
        float acc = 0.f;
        #pragma unroll
        for (int wg = 0; wg < 8; ++wg) acc += sfb[wg][t] * __expf(smax[wg][m] - gmx);
        pfbar[(size_t)(pb + m) * 256 + t] = acc;
        if (t == 0) {
            float gs = 0.f;
            #pragma unroll
            for (int wg = 0; wg < 8; ++wg) gs += ssum[wg][m] * __expf(smax[wg][m] - gmx);
            pmax[pb + m] = gmx; psum[pb + m] = gs;
        }
    }
}

// ---- combine partials; g=fbar@Wv; query=sum g@Wo; q2=query@Wq2 ----
__global__ __launch_bounds__(256) void k_combine(const float* __restrict__ pmax,
        const float* __restrict__ psum, const float* __restrict__ pfbar,
        const float* __restrict__ Wv, const float* __restrict__ Wo,
        const float* __restrict__ Wq2, float* __restrict__ q2ws, float* __restrict__ outq) {
    int b = blockIdx.x, t = threadIdx.x;
    __shared__ float lpm[SPLITS][NHEAD], lps[SPLITS][NHEAD], gm[NHEAD], tm[NHEAD];
    __shared__ float fbar[NHEAD][256];
    __shared__ float g[NHEAD][256];
    __shared__ float qn[256];
    if (t < SPLITS * NHEAD) {
        int s = t >> 2, m = t & 3;
        lpm[s][m] = pmax[(b * SPLITS + s) * NHEAD + m];
        lps[s][m] = psum[(b * SPLITS + s) * NHEAD + m];
    }
    __syncthreads();
    if (t < NHEAD) {
        float gmx = -__builtin_huge_valf();
        for (int s = 0; s < SPLITS; ++s) gmx = fmaxf(gmx, lpm[s][t]);
        float ts = 0.f;
        for (int s = 0; s < SPLITS; ++s) ts += lps[s][t] * __expf(lpm[s][t] - gmx);
        gm[t] = gmx; tm[t] = ts;
    }
    __syncthreads();
    #pragma unroll
    for (int m = 0; m < NHEAD; ++m) {
        float fbv = 0.f;
        for (int s = 0; s < SPLITS; ++s)
            fbv += pfbar[(size_t)((b * SPLITS + s) * NHEAD + m) * 256 + t] * __expf(lpm[s][m] - gm[m]);
        fbar[m][t] = fbv / tm[m];
    }
    __syncthreads();
    #pragma unroll
    for (int m = 0; m < NHEAD; ++m) {
        float acc = 0.f;
        for (int d = 0; d < 256; ++d) acc += fbar[m][d] * Wv[(m * 256 + d) * 256 + t];
        g[m][t] = acc;
    }
    __syncthreads();
    {
        float acc = 0.f;
        #pragma unroll
        for (int m = 0; m < NHEAD; ++m)
            for (int e = 0; e < 256; ++e) acc += g[m][e] * Wo[(m * 256 + e) * 256 + t];
        qn[t] = acc;
        outq[b * 256 + t] = acc;
    }
    __syncthreads();
    {
        float acc = 0.f;
        for (int d = 0; d < 256; ++d) acc += qn[d] * Wq2[d * 256 + t];
        q2ws[b * 256 + t] = acc;
    }
}

// ---- pointer head: LDS-staged MFMA, in-kernel cross-wave reduce, pipelined flush ----
__global__ __launch_bounds__(256, 2) void k_pointer(const float* __restrict__ feat,
        const int* __restrict__ mask, const unsigned short* __restrict__ wpack,
        const float* __restrict__ q2, const float* __restrict__ vec2,
        float* __restrict__ u) {
    const int tid = threadIdx.x;
    const int w = tid >> 6, l = tid & 63;
    const int lr = l & 15, lg = l >> 4;
    bf16x8 bf[8][4];
    #pragma unroll
    for (int kt = 0; kt < 8; ++kt)
        #pragma unroll
        for (int i = 0; i < 4; ++i) {
            int frag = kt * 16 + (w * 4 + i);
            bf[kt][i] = *(const bf16x8*)(wpack + ((frag << 6) + l) * 8);
        }
    float v2[4];
    #pragma unroll
    for (int i = 0; i < 4; ++i) v2[i] = vec2[w * 64 + i * 16 + lr];

    __shared__ char AB[16384];           // 2 x [16 rows][256 bf16], XOR-swizzled
    __shared__ float lu[2][4][16];
    const int srow = tid >> 4, sc = tid & 15;
    const int swz = (srow & 7) << 4;
    const int NT = (B * NPTS) / 16;      // 16000

    int t0 = blockIdx.x;
    {   // prologue: stage tile t0 into buffer 0
        const float* gp = feat + ((size_t)(t0 * 16 + srow) << 8) + sc * 16;
        f32x4 a = *(const f32x4*)(gp + 0), b4 = *(const f32x4*)(gp + 4);
        f32x4 cc = *(const f32x4*)(gp + 8), d = *(const f32x4*)(gp + 12);
        bf16x8 h0, h1;
        h0[0]=(__bf16)a.x; h0[1]=(__bf16)a.y; h0[2]=(__bf16)a.z; h0[3]=(__bf16)a.w;
        h0[4]=(__bf16)b4.x; h0[5]=(__bf16)b4.y; h0[6]=(__bf16)b4.z; h0[7]=(__bf16)b4.w;
        h1[0]=(__bf16)cc.x; h1[1]=(__bf16)cc.y; h1[2]=(__bf16)cc.z; h1[3]=(__bf16)cc.w;
        h1[4]=(__bf16)d.x; h1[5]=(__bf16)d.y; h1[6]=(__bf16)d.z; h1[7]=(__bf16)d.w;
        *(bf16x8*)(AB + srow * 512 + ((sc * 32) ^ swz)) = h0;
        *(bf16x8*)(AB + srow * 512 + ((sc * 32 + 16) ^ swz)) = h1;
    }
    int cur = 0;
    int tprev = -1;
    for (int t = t0; t < NT; t += PGRID) {
        int tn = t + PGRID;
        bool has = tn < NT;
        int tl = has ? tn : t;
        const float* gp = feat + ((size_t)(tl * 16 + srow) << 8) + sc * 16;
        f32x4 pa = *(const f32x4*)(gp + 0), pb = *(const f32x4*)(gp + 4);
        f32x4 pc = *(const f32x4*)(gp + 8), pd = *(const f32x4*)(gp + 12);

        __syncthreads();                 // buf[cur] staged; prev lu[cur^1] written
        // flush previous tile's u
        if (tprev >= 0 && tid < 16) {
            float tot = lu[cur ^ 1][0][tid] + lu[cur ^ 1][1][tid]
                      + lu[cur ^ 1][2][tid] + lu[cur ^ 1][3][tid];
            int pbb = tprev / 125;
            int pn = (tprev - pbb * 125) * 16 + tid;
            float uu = mask[pbb * NPTS + pn] ? 10.f * ftanh(tot) : NEGV;
            u[pbb * NPTS + pn] = uu;
        }
        // compute tile t from buf[cur]
        int b = t / 125;
        int n0 = (t - b * 125) * 16;
        float q2v[4];
        #pragma unroll
        for (int i = 0; i < 4; ++i) q2v[i] = q2[b * 256 + w * 64 + i * 16 + lr];
        f32x4 acc[4];
        #pragma unroll
        for (int i = 0; i < 4; ++i) acc[i] = 0.f;
        const char* rb = AB + cur * 8192 + lr * 512;
        const int rswz = (lr & 7) << 4;
        #pragma unroll
        for (int kt = 0; kt < 8; ++kt) {
            bf16x8 af = *(const bf16x8*)(rb + ((kt * 64 + lg * 16) ^ rswz));
            #pragma unroll
            for (int i = 0; i < 4; ++i)
                acc[i] = __builtin_amdgcn_mfma_f32_16x16x32_bf16(af, bf[kt][i], acc[i], 0, 0, 0);
        }
        float s0 = 0.f, s1 = 0.f, s2 = 0.f, s3 = 0.f;
        #pragma unroll
        for (int i = 0; i < 4; ++i) {
            float qv = q2v[i], vv = v2[i];
            s0 += ftanh(acc[i][0] + qv) * vv;
            s1 += ftanh(acc[i][1] + qv) * vv;
            s2 += ftanh(acc[i][2] + qv) * vv;
            s3 += ftanh(acc[i][3] + qv) * vv;
        }
        #pragma unroll
        for (int off = 1; off < 16; off <<= 1) {
            s0 += __shfl_xor(s0, off, 64);
            s1 += __shfl_xor(s1, off, 64);
            s2 += __shfl_xor(s2, off, 64);
            s3 += __shfl_xor(s3, off, 64);
        }
        if (lr == 0) {
            lu[cur][w][lg * 4 + 0] = s0; lu[cur][w][lg * 4 + 1] = s1;
            lu[cur][w][lg * 4 + 2] = s2; lu[cur][w][lg * 4 + 3] = s3;
        }
        // stage prefetched tile into buf[cur^1]
        if (has) {
            bf16x8 h0, h1;
            h0[0]=(__bf16)pa.x; h0[1]=(__bf16)pa.y; h0[2]=(__bf16)pa.z; h0[3]=(__bf16)pa.w;
            h0[4]=(__bf16)pb.x; h0[5]=(__bf16)pb.y; h0[6]=(__bf16)pb.z; h0[7]=(__bf16)pb.w;
            h1[0]=(__bf16)pc.x; h1[1]=(__bf16)pc.y; h1[2]=(__bf16)pc.z; h1[3]=(__bf16)pc.w;
            h1[4]=(__bf16)pd.x; h1[5]=(__bf16)pd.y; h1[6]=(__bf16)pd.z; h1[7]=(__bf16)pd.w;
            char* wb = AB + (cur ^ 1) * 8192 + srow * 512;
            *(bf16x8*)(wb + ((sc * 32) ^ swz)) = h0;
            *(bf16x8*)(wb + ((sc * 32 + 16) ^ swz)) = h1;
        }
        tprev = t; cur ^= 1;
    }
    __syncthreads();
    if (tprev >= 0 && tid < 16) {        // flush last tile (its lu is lu[cur^1] after toggle)
        float tot = lu[cur ^ 1][0][tid] + lu[cur ^ 1][1][tid]
                  + lu[cur ^ 1][2][tid] + lu[cur ^ 1][3][tid];
        int pbb = tprev / 125;
        int pn = (tprev - pbb * 125) * 16 + tid;
        float uu = mask[pbb * NPTS + pn] ? 10.f * ftanh(tot) : NEGV;
        u[pbb * NPTS + pn] = uu;
    }
}

// ---- log-softmax with fixed max bound (|u| <= 10 or NEGV) ----
__global__ __launch_bounds__(256) void k_lse(const float* __restrict__ u, float* __restrict__ outp) {
    int b = blockIdx.x, t = threadIdx.x;
    float uv[8];
    int cnt = 0;
    float sm = 0.f;
    for (int i = t; i < NPTS; i += 256) {
        uv[cnt] = u[b * NPTS + i];
        sm += __expf(uv[cnt] - 10.f);
        ++cnt;
    }
    __shared__ float red[4];
    #pragma unroll
    for (int off = 1; off < 64; off <<= 1) sm += __shfl_xor(sm, off, 64);
    int w = t >> 6, l = t & 63;
    if (l == 0) red[w] = sm;
    __syncthreads();
    sm = red[0] + red[1] + red[2] + red[3];
    float lse = 10.f + __logf(sm);
    cnt = 0;
    for (int i = t; i < NPTS; i += 256) { outp[b * NPTS + i] = uv[cnt] - lse; ++cnt; }
}

extern "C" void kernel_launch(void* const* d_in, const int* in_sizes, int n_in,
                              void* d_out, int out_size, void* d_ws, size_t ws_size,
                              hipStream_t stream) {
    const float* feat = (const float*)d_in[0];
    const float* raw  = (const float*)d_in[1];
    const int*   mask = (const int*)d_in[2];
    const float* E1 = (const float*)d_in[3];
    const float* b1 = (const float*)d_in[4];
    const float* E2 = (const float*)d_in[5];
    const float* b2 = (const float*)d_in[6];
    const float* E3 = (const float*)d_in[7];
    const float* b3 = (const float*)d_in[8];
    const float* Wq = (const float*)d_in[9];
    const float* Wk = (const float*)d_in[10];
    const float* Wv = (const float*)d_in[11];
    const float* Wo = (const float*)d_in[12];
    const float* Wq2 = (const float*)d_in[13];
    const float* Wref2 = (const float*)d_in[14];
    const float* Vec2 = (const float*)d_in[15];
    const float* v1 = (const float*)d_in[16];
    float* out = (float*)d_out;

    char* ws = (char*)d_ws;
    float* queryws = (float*)(ws + 0);             // 131072 B
    float* qtilws  = (float*)(ws + 131072);        // 524288 B
    float* pmax    = (float*)(ws + 655360);        // 16384 B
    float* psum    = (float*)(ws + 671744);        // 16384 B
    float* pfbar   = (float*)(ws + 688128);        // 4194304 B
    float* q2ws    = (float*)(ws + 4882432);       // 131072 B
    unsigned short* wpack = (unsigned short*)(ws + 5013504);  // 131072 B
    float* uws     = (float*)(ws + 5144576);       // 1024000 B
    float* outq = out + B * NPTS;

    hipLaunchKernelGGL(k_prep, dim3(B + 64), dim3(256), 0, stream,
                       raw, E1, b1, E2, b2, E3, b3, v1, Wq, Wk, Wref2,
                       queryws, qtilws, wpack);
    hipLaunchKernelGGL(k_glimpse, dim3(B * SPLITS), dim3(256), 0, stream,
                       feat, mask, qtilws, pmax, psum, pfbar);
    hipLaunchKernelGGL(k_combine, dim3(B), dim3(256), 0, stream,
                       pmax, psum, pfbar, Wv, Wo, Wq2, q2ws, outq);
    hipLaunchKernelGGL(k_pointer, dim3(PGRID), dim3(256), 0, stream,
                       feat, mask, wpack, q2ws, Vec2, uws);
    hipLaunchKernelGGL(k_lse, dim3(B), dim3(256), 0, stream, uws, out);
}